// Round 6
// baseline (499.134 us; speedup 1.0000x reference)
//
#include <hip/hip_runtime.h>
#include <hip/hip_bf16.h>
#include <stdint.h>

typedef uint32_t u32;
typedef unsigned short u16;
typedef float v2f __attribute__((ext_vector_type(2)));

#define NLAT_I 361
#define NLON_I 720
#define NLAT_O 181
#define NLON_O 360
#define KK 9
#define NNZ 120000
#define NSEG (KK * NLAT_O)            /* 1629 */
#define NPIX (NLAT_O * NLON_O)        /* 65160 */
#define NCH 32
#define SORT_CAP 512
#define ROWLEN 5760                   /* u32 words per (hi,p) row: 360*16 */
#define ROWBYTES 23040                /* bytes per row */
#define ROWCHUNK 1440                 /* 16B chunks per row */

/* stage1 persistent geometry: 233 blocks x 7 segs = 1631 >= 1629, all co-resident */
#define NBLK1 233
#define SEGS_PER_BLK 7
#define NC 8                          /* sorted-hi phases */
#define LDSCAP 160                    /* staged recs per segment (max cnt ~110) */
#define SPIN_LIMIT 100

#define AS1 __attribute__((address_space(1)))
#define AS3 __attribute__((address_space(3)))

__device__ __forceinline__ u32 f2bf_rne(float f) {
    u32 b = __float_as_uint(f);
    return (b + 0x7FFFu + ((b >> 16) & 1u)) >> 16;
}

__device__ __forceinline__ int imin(int a, int b) { return a < b ? a : b; }

// ---------------- repack: x[32][361][720] f32 -> xp[hi*2+p][j][cp] bf16x2 ---
__global__ __launch_bounds__(256) void repack_kernel(const float* __restrict__ x,
                                                     u32* __restrict__ xp) {
    __shared__ u16 tile[32][732];
    int hi = blockIdx.x;               // 361 blocks
    int tid = threadIdx.x;
    const size_t plane = (size_t)NLAT_I * NLON_I;
#pragma unroll 1
    for (int c = 0; c < NCH; c++) {
        for (int col = tid; col < NLON_I; col += 256) {
            tile[c][col] = (u16)f2bf_rne(x[c * plane + (size_t)hi * NLON_I + col]);
        }
    }
    __syncthreads();
    for (int wdx = tid; wdx < 2 * ROWLEN; wdx += 256) {
        int p = wdx / ROWLEN;
        int rem = wdx - p * ROWLEN;
        int j = rem >> 4;
        int cp = rem & 15;
        int col = 2 * j + p;
        u32 v = (u32)tile[2 * cp][col] | ((u32)tile[2 * cp + 1][col] << 16);
        xp[(size_t)(2 * hi + p) * ROWLEN + rem] = v;
    }
}

// ---------------- CSR build ------------------------------------------------
__global__ __launch_bounds__(256) void hist_kernel(const int* __restrict__ ker,
                                                   const int* __restrict__ row,
                                                   int* __restrict__ counts) {
    int e = blockIdx.x * 256 + threadIdx.x;
    if (e >= NNZ) return;
    int seg = ker[e] * NLAT_O + row[e];
    atomicAdd(&counts[seg], 1);
}

__global__ __launch_bounds__(256) void scan_kernel(const int* __restrict__ counts,
                                                   int* __restrict__ offsets) {
    __shared__ int lsum[256];
    const int CH = 7;                  // 256*7 = 1792 >= 1629
    int t = threadIdx.x;
    int base = t * CH;
    int local[CH];
    int s = 0;
    for (int i = 0; i < CH; i++) {
        int v = (base + i < NSEG) ? counts[base + i] : 0;
        local[i] = s;
        s += v;
    }
    lsum[t] = s;
    __syncthreads();
    for (int off = 1; off < 256; off <<= 1) {
        int v = 0;
        if (t >= off) v = lsum[t - off];
        __syncthreads();
        if (t >= off) lsum[t] += v;
        __syncthreads();
    }
    int pre = (t == 0) ? 0 : lsum[t - 1];
    for (int i = 0; i < CH; i++) {
        if (base + i < NSEG) offsets[base + i] = pre + local[i];
    }
}

__global__ __launch_bounds__(256) void scatter_kernel(const int* __restrict__ ker,
                                                      const int* __restrict__ row,
                                                      const int* __restrict__ col,
                                                      const float* __restrict__ vals,
                                                      const int* __restrict__ offsets,
                                                      int* __restrict__ cursor,
                                                      int2* __restrict__ recs) {
    int e = blockIdx.x * 256 + threadIdx.x;
    if (e >= NNZ) return;
    int seg = ker[e] * NLAT_O + row[e];
    int pos = offsets[seg] + atomicAdd(&cursor[seg], 1);
    int c  = col[e];
    int hi = c / NLON_I;
    int wi = c % NLON_I;
    int p  = wi & 1;
    int a  = wi >> 1;                  // < 360
    u32 meta = ((u32)hi << 10) | ((u32)p << 9) | (u32)a;
    recs[pos] = make_int2((int)meta, __float_as_int(vals[e]));
}

// ---------------- per-segment sort by meta (hi,p,a ascending) --------------
__global__ __launch_bounds__(256) void sort_kernel(const int* __restrict__ offs,
                                                   const int* __restrict__ cnts,
                                                   int2* __restrict__ recs) {
    __shared__ u32 skey[SORT_CAP];
    __shared__ u32 sval[SORT_CAP];
    int s = blockIdx.x;
    int start = offs[s];
    int cnt = cnts[s];
    if (cnt > SORT_CAP) return;       // perf-only transform; safe to skip
    int t = threadIdx.x;
    for (int i = t; i < cnt; i += 256) {
        int2 r = recs[start + i];
        skey[i] = (u32)r.x;
        sval[i] = (u32)r.y;
    }
    __syncthreads();
    for (int i = t; i < cnt; i += 256) {
        u32 k = skey[i];
        int rank = 0;
        for (int j = 0; j < cnt; j++) {
            u32 kj = skey[j];
            rank += (kj < k || (kj == k && j < i)) ? 1 : 0;
        }
        recs[start + rank] = make_int2((int)k, (int)sval[i]);
    }
}

// ---------------- stage1: persistent, LDS-row-ring pipelined ---------------
// Each entry's (hi,p) row (23KB) is consumed in FULL by the block (360 wo x
// 2 halves read every byte once). So: stream rows into a 4-deep LDS ring via
// global_load_lds (2 instr/wave/row), consume via ds_read_b128, counted
// vmcnt(4) + raw s_barrier per entry -> 3 rows always in flight. 16B chunks
// are rotated within each 128B block (sigma) to kill ds_read bank conflicts;
// staging pre-swizzles the per-lane GLOBAL address, LDS writes stay linear.

#define FMA8(q0, q1, vv, A)                 \
    {                                       \
        A[0] = bf2(q0.x) * vv + A[0];       \
        A[1] = bf2(q0.y) * vv + A[1];       \
        A[2] = bf2(q0.z) * vv + A[2];       \
        A[3] = bf2(q0.w) * vv + A[3];       \
        A[4] = bf2(q1.x) * vv + A[4];       \
        A[5] = bf2(q1.y) * vv + A[5];       \
        A[6] = bf2(q1.z) * vv + A[6];       \
        A[7] = bf2(q1.w) * vv + A[7];       \
    }

__device__ __forceinline__ v2f bf2(u32 u) {
    v2f r;
    r.x = __uint_as_float(u << 16);
    r.y = __uint_as_float(u & 0xFFFF0000u);
    return r;
}

__global__ __launch_bounds__(768, 3) void stage1_kernel(const u32* __restrict__ xp,
                                                        const int* __restrict__ offs,
                                                        const int* __restrict__ cnts,
                                                        const int2* __restrict__ recs,
                                                        int* __restrict__ ctr,
                                                        u16* __restrict__ xk) {
    __shared__ uint4 ring4[4][ROWCHUNK];            // 92160 B
    __shared__ int2 lrec[SEGS_PER_BLK][LDSCAP];     // 8960 B
    __shared__ u32 frow[SEGS_PER_BLK * LDSCAP + 8]; // flat row ids + pad
    __shared__ int scnt[8], soff[8];
    __shared__ int cbase[NC][SEGS_PER_BLK];
    __shared__ int s_tot;

    int b = blockIdx.x;
    int tid = threadIdx.x;
    int lane = tid & 63;
    int wv = tid >> 6;                 // 0..11

    if (tid < SEGS_PER_BLK) {
        int s = b * SEGS_PER_BLK + tid;
        int ok = (s < NSEG);
        scnt[tid] = ok ? cnts[s] : 0;
        soff[tid] = ok ? offs[s] : 0;
    }
    __syncthreads();

#pragma unroll
    for (int slot = 0; slot < SEGS_PER_BLK; slot++) {
        int c = imin(scnt[slot], LDSCAP);
        int o = soff[slot];
        for (int i = tid; i < c; i += 768) lrec[slot][i] = recs[o + i];
    }
    __syncthreads();

    if (tid == 0) {
        int g = 0;
        for (int c = 0; c < NC; c++)
            for (int slot = 0; slot < SEGS_PER_BLK; slot++) {
                cbase[c][slot] = g;
                int cc = imin(scnt[slot], LDSCAP);
                g += ((c + 1) * cc) / NC - (c * cc) / NC;
            }
        s_tot = g;
        frow[g] = 0; frow[g + 1] = 0; frow[g + 2] = 0;   // pipeline tail pad
    }
    __syncthreads();
    if (tid < NC * SEGS_PER_BLK) {
        int c = tid / SEGS_PER_BLK, slot = tid % SEGS_PER_BLK;
        int cc = imin(scnt[slot], LDSCAP);
        int beg = (c * cc) / NC, end = ((c + 1) * cc) / NC;
        int base = cbase[c][slot];
        for (int i = beg; i < end; i++)
            frow[base + (i - beg)] = ((u32)lrec[slot][i].x) >> 9;
    }
    __syncthreads();
    int tot = s_tot;

    int wo = tid >> 1, h = tid & 1;
    bool act = wo < NLON_O;
    int w = act ? wo : 0;
    const char* xpb = (const char*)xp;

    // staging constants: wave wv covers LDS chunk slots [wv*120, wv*120+120)
    int sl0 = wv * 120 + lane;
    int sl1 = wv * 120 + 64 + lane;
    // sigma^-1(s) = (s&~7) | ((s - (s>>3)) & 7): global chunk for LDS slot s
    size_t goff0 = (size_t)((sl0 & ~7) | ((sl0 - (sl0 >> 3)) & 7)) * 16;
    size_t goff1 = (size_t)((sl1 & ~7) | ((sl1 - (sl1 >> 3)) & 7)) * 16;
    bool lane1ok = lane < 56;          // 120 = 64 + 56 chunks per wave
    int wvb = wv * 120;

    v2f acc[SEGS_PER_BLK][8];
#pragma unroll
    for (int slot = 0; slot < SEGS_PER_BLK; slot++)
#pragma unroll
        for (int j = 0; j < 8; j++) acc[slot][j] = (v2f){0.0f, 0.0f};

    // prologue: stage rows 0..2 (frow padded, safe for tot<3)
#pragma unroll
    for (int r = 0; r < 3; r++) {
        const char* rb = xpb + (size_t)frow[r] * ROWBYTES;
        __builtin_amdgcn_global_load_lds((const AS1 void*)(rb + goff0),
                                         (AS3 void*)&ring4[r][wvb], 16, 0, 0);
        if (lane1ok)
            __builtin_amdgcn_global_load_lds((const AS1 void*)(rb + goff1),
                                             (AS3 void*)&ring4[r][wvb + 64], 16, 0, 0);
    }

    int g = 0;
    for (int c = 0; c < NC; c++) {
#pragma unroll
        for (int slot = 0; slot < SEGS_PER_BLK; slot++) {
            int cc = imin(scnt[slot], LDSCAP);
            int beg = (c * cc) / NC;
            int end = ((c + 1) * cc) / NC;
#pragma unroll 1
            for (int i = beg; i < end; i++) {
                // row g staged (my 2 oldest vm ops retired) ...
                asm volatile("s_waitcnt vmcnt(4)" ::: "memory");
                // ... and everyone else's too:
                __builtin_amdgcn_s_barrier();
                asm volatile("" ::: "memory");
                __builtin_amdgcn_sched_barrier(0);

                int2 r = lrec[slot][i];
                int a = r.x & 0x1FF;
                float vf = __int_as_float(r.y);
                v2f vv = {vf, vf};
                int idx = a + w;
                idx = (idx >= NLON_O) ? idx - NLON_O : idx;
                int c0 = (idx << 2) + (h << 1);
                int bb = c0 >> 3;
                int t0 = c0 + bb;
                int s0 = (c0 & ~7) | (t0 & 7);
                int s1 = (c0 & ~7) | ((t0 + 1) & 7);
                const uint4* rb4 = &ring4[g & 3][0];
                uint4 q0 = rb4[s0];
                uint4 q1 = rb4[s1];
                FMA8(q0, q1, vv, acc[slot])

                // stage row g+3 into ring[(g+3)&3] (overwrites g-1: all waves
                // finished it before this barrier)
                u32 nrow = frow[g + 3];
                const char* nb = xpb + (size_t)nrow * ROWBYTES;
                int buf = (g + 3) & 3;
                __builtin_amdgcn_global_load_lds((const AS1 void*)(nb + goff0),
                                                 (AS3 void*)&ring4[buf][wvb], 16, 0, 0);
                if (lane1ok)
                    __builtin_amdgcn_global_load_lds((const AS1 void*)(nb + goff1),
                                                     (AS3 void*)&ring4[buf][wvb + 64],
                                                     16, 0, 0);
                g++;
            }
        }
        if (c < NC - 1) {
            // cross-block quasi-barrier: keeps all co-resident blocks in the
            // same sorted-hi window (L2 locality). Deadlock-free (capped spin);
            // __syncthreads here drains vmcnt(0) -- counting stays valid.
            __syncthreads();
            if (tid == 0) {
                __hip_atomic_fetch_add(&ctr[c], 1, __ATOMIC_RELAXED,
                                       __HIP_MEMORY_SCOPE_AGENT);
                int spins = 0;
                while (spins < SPIN_LIMIT &&
                       __hip_atomic_load(&ctr[c], __ATOMIC_RELAXED,
                                         __HIP_MEMORY_SCOPE_AGENT) < (int)gridDim.x) {
                    __builtin_amdgcn_s_sleep(2);
                    ++spins;
                }
            }
            __syncthreads();
        }
    }

    // overflow safety net: entries beyond LDSCAP via direct global gather
#pragma unroll
    for (int slot = 0; slot < SEGS_PER_BLK; slot++) {
        int cnt = scnt[slot];
        if (cnt > LDSCAP) {
            const int2* rg = recs + soff[slot];
            const u32* xph = xp + h * 8;
#pragma unroll 1
            for (int i = LDSCAP; i < cnt; i++) {
                int2 r0 = rg[i];
                u32 m0 = (u32)r0.x;
                float vf = __int_as_float(r0.y);
                v2f vv = {vf, vf};
                int row0 = (int)(m0 >> 9);
                int a0 = (int)(m0 & 0x1FF);
                int idx0 = a0 + w;
                idx0 = (idx0 >= NLON_O) ? idx0 - NLON_O : idx0;
                const uint4* rp = (const uint4*)(xph + ((size_t)(row0 * NLON_O + idx0) << 4));
                uint4 q0 = rp[0];
                uint4 q1 = rp[1];
                FMA8(q0, q1, vv, acc[slot])
            }
        }
    }

    if (act) {
#pragma unroll
        for (int slot = 0; slot < SEGS_PER_BLK; slot++) {
            int s = b * SEGS_PER_BLK + slot;
            if (s < NSEG) {
                int k = s / NLAT_O;
                int ho = s - k * NLAT_O;
                int pix = ho * NLON_O + wo;
#pragma unroll
                for (int j = 0; j < 8; j++) {
                    int ch = h * 16 + 2 * j;
                    xk[(size_t)(ch * KK + k) * NPIX + pix] =
                        (u16)f2bf_rne(acc[slot][j].x);
                    xk[(size_t)((ch + 1) * KK + k) * NPIX + pix] =
                        (u16)f2bf_rne(acc[slot][j].y);
                }
            }
        }
    }
}

// ---------------- stage2: out[32][65160] = W[32][288] * xk[288][65160] -----
__global__ __launch_bounds__(256) void stage2_kernel(const u16* __restrict__ xk,
                                                     const float* __restrict__ W,
                                                     const float* __restrict__ bias,
                                                     float* __restrict__ out) {
    int t = blockIdx.x * 256 + threadIdx.x;    // pix-pair id
    bool act = t < NPIX / 2;
    int px = act ? t : 0;
    const u32* xk32 = (const u32*)xk;
    float a0[NCH], a1[NCH];
#pragma unroll
    for (int o = 0; o < NCH; o++) { a0[o] = 0.0f; a1[o] = 0.0f; }
#pragma unroll 4
    for (int r = 0; r < NCH * KK; r++) {
        u32 u = xk32[(size_t)r * (NPIX / 2) + px];
        float x0 = __uint_as_float(u << 16);
        float x1 = __uint_as_float(u & 0xFFFF0000u);
#pragma unroll
        for (int o = 0; o < NCH; o++) {
            float wv = W[o * (NCH * KK) + r];
            a0[o] = fmaf(wv, x0, a0[o]);
            a1[o] = fmaf(wv, x1, a1[o]);
        }
    }
    if (act) {
#pragma unroll
        for (int o = 0; o < NCH; o++) {
            float2 v = make_float2(a0[o] + bias[o], a1[o] + bias[o]);
            *(float2*)(out + (size_t)o * NPIX + 2 * t) = v;
        }
    }
}

// ---------------- launch ---------------------------------------------------
extern "C" void kernel_launch(void* const* d_in, const int* in_sizes, int n_in,
                              void* d_out, int out_size, void* d_ws, size_t ws_size,
                              hipStream_t stream) {
    const float* x    = (const float*)d_in[0];
    const int* ker    = (const int*)d_in[1];
    const int* row    = (const int*)d_in[2];
    const int* col    = (const int*)d_in[3];
    const float* vals = (const float*)d_in[4];
    const float* W    = (const float*)d_in[5];
    const float* bias = (const float*)d_in[6];
    float* out        = (float*)d_out;

    char* ws = (char*)d_ws;
    const size_t off_xp   = 0;
    const size_t sz_xp    = (size_t)NLAT_I * 2 * ROWLEN * 4;   // 16,634,880
    const size_t off_cnt  = off_xp + sz_xp;
    const size_t off_off  = off_cnt + 6528;
    const size_t off_cur  = off_off + 6528;
    const size_t off_ctr  = off_cur + 6528;                    // 64 B (NC ints)
    const size_t off_rec  = off_ctr + 64;                      // 8-aligned
    const size_t off_xk   = off_rec + (size_t)NNZ * 8;

    u32* xp      = (u32*)(ws + off_xp);
    int* counts  = (int*)(ws + off_cnt);
    int* offsets = (int*)(ws + off_off);
    int* cursor  = (int*)(ws + off_cur);
    int* ctr     = (int*)(ws + off_ctr);
    int2* recs   = (int2*)(ws + off_rec);
    u16* xk      = (u16*)(ws + off_xk);

    // zero counts + offsets + cursor + barrier counters
    hipMemsetAsync(ws + off_cnt, 0, 3 * 6528 + 64, stream);

    repack_kernel<<<NLAT_I, 256, 0, stream>>>(x, xp);
    hist_kernel<<<(NNZ + 255) / 256, 256, 0, stream>>>(ker, row, counts);
    scan_kernel<<<1, 256, 0, stream>>>(counts, offsets);
    scatter_kernel<<<(NNZ + 255) / 256, 256, 0, stream>>>(ker, row, col, vals,
                                                          offsets, cursor, recs);
    sort_kernel<<<NSEG, 256, 0, stream>>>(offsets, counts, recs);
    stage1_kernel<<<NBLK1, 768, 0, stream>>>(xp, offsets, counts, recs, ctr, xk);
    stage2_kernel<<<(NPIX / 2 + 255) / 256, 256, 0, stream>>>(xk, W, bias, out);
}